// Round 1
// baseline (1151.866 us; speedup 1.0000x reference)
//
#include <hip/hip_runtime.h>
#include <hip/hip_bf16.h>

// Problem constants (T5 self-attention)
#define BB 4
#define SS 1024
#define HH 16
#define DK 64
#define DM 1024
#define MM (BB * SS)  // 4096

// T5 relative position bucket (bidirectional), faithful to reference f32 math.
// rel = mem - ctx = k - q
__device__ __forceinline__ int rel_bucket(int rel) {
    int n = -rel;               // q - k
    int ret = 0;
    if (n < 0) { ret = 16; n = -n; }
    int v;
    if (n < 8) {
        v = n;
    } else {
        // log(n/8) / log(128/8) * (16-8), f32 arithmetic, truncate toward zero
        float t = logf((float)n * 0.125f) / 2.7725887298583984f * 8.0f;
        v = 8 + (int)t;
        if (v > 15) v = 15;
    }
    return ret + v;
}

// ---------------------------------------------------------------------------
// Kernel 1: fused QKV projection.  q = X @ W^T  (A row-major MxK, W row-major NxK)
// Writes [B,H,S,D] layout. 64x64 tile, BK=16, 256 threads, 4x4 microtile.
// ---------------------------------------------------------------------------
__global__ __launch_bounds__(256)
void k_proj_qkv(const float* __restrict__ X,
                const float* __restrict__ Wq,
                const float* __restrict__ Wk,
                const float* __restrict__ Wv,
                float* __restrict__ Q,
                float* __restrict__ Kp,
                float* __restrict__ V) {
    const int z = blockIdx.z;
    const float* W = (z == 0) ? Wq : (z == 1) ? Wk : Wv;
    float* O = (z == 0) ? Q : (z == 1) ? Kp : V;

    __shared__ float As[16][68];  // [k][m], pad->16B-aligned float4 reads
    __shared__ float Bs[16][68];  // [k][n]

    const int tid = threadIdx.x;
    const int m0 = blockIdx.y * 64;
    const int n0 = blockIdx.x * 64;
    const int lr = tid >> 2;         // 0..63
    const int lc = (tid & 3) * 4;    // 0,4,8,12
    const int ty = tid >> 4;         // 0..15
    const int tx = tid & 15;         // 0..15

    float acc[4][4] = {};

    for (int k0 = 0; k0 < DM; k0 += 16) {
        float4 a = *(const float4*)(X + (size_t)(m0 + lr) * DM + k0 + lc);
        float4 b = *(const float4*)(W + (size_t)(n0 + lr) * DM + k0 + lc);
        __syncthreads();
        As[lc + 0][lr] = a.x; As[lc + 1][lr] = a.y; As[lc + 2][lr] = a.z; As[lc + 3][lr] = a.w;
        Bs[lc + 0][lr] = b.x; Bs[lc + 1][lr] = b.y; Bs[lc + 2][lr] = b.z; Bs[lc + 3][lr] = b.w;
        __syncthreads();
#pragma unroll
        for (int kk = 0; kk < 16; ++kk) {
            float4 av = *(const float4*)&As[kk][ty * 4];
            float4 bv = *(const float4*)&Bs[kk][tx * 4];
            float a_[4] = {av.x, av.y, av.z, av.w};
            float b_[4] = {bv.x, bv.y, bv.z, bv.w};
#pragma unroll
            for (int i = 0; i < 4; ++i)
#pragma unroll
                for (int j = 0; j < 4; ++j)
                    acc[i][j] = fmaf(a_[i], b_[j], acc[i][j]);
        }
    }

    // scatter to [B,H,S,D]; n-tile (64) aligns exactly with one head
    const int e0 = n0 + tx * 4;
    const int h = e0 >> 6, dk = e0 & 63;
#pragma unroll
    for (int i = 0; i < 4; ++i) {
        const int m = m0 + ty * 4 + i;
        const int b = m >> 10, s = m & 1023;
        float4 o = make_float4(acc[i][0], acc[i][1], acc[i][2], acc[i][3]);
        *(float4*)(O + ((size_t)((b * HH + h) * SS + s)) * DK + dk) = o;
    }
}

// ---------------------------------------------------------------------------
// Kernel 2: raw scores = QK^T/8 + bias, mask applied; written to P (d_out region)
// One block: 64 q-rows x 64 k-cols for one (b,h). K-dim = 64 (single pass).
// ---------------------------------------------------------------------------
__global__ __launch_bounds__(256)
void k_scores(const float* __restrict__ Q,
              const float* __restrict__ Kp,
              const int* __restrict__ mask,
              const float* __restrict__ rel_bias,
              float* __restrict__ P) {
    __shared__ float Qs[64][68];
    __shared__ float Ks[64][68];
    __shared__ float biasS[128];
    __shared__ int maskS[64];

    const int bh = blockIdx.z;
    const int b = bh >> 4, h = bh & 15;
    const int q0 = blockIdx.y * 64;
    const int k0 = blockIdx.x * 64;
    const int tid = threadIdx.x;

    {
        const int lr = tid >> 2;
        const int lc = (tid & 3) * 16;
        const float* qrow = Q + ((size_t)bh * SS + q0 + lr) * DK + lc;
        const float* krow = Kp + ((size_t)bh * SS + k0 + lr) * DK + lc;
#pragma unroll
        for (int u = 0; u < 4; ++u) {
            *(float4*)&Qs[lr][lc + 4 * u] = *(const float4*)(qrow + 4 * u);
            *(float4*)&Ks[lr][lc + 4 * u] = *(const float4*)(krow + 4 * u);
        }
    }
    if (tid < 127) {
        const int rel = (k0 - q0) + tid - 63;
        biasS[tid] = rel_bias[rel_bucket(rel) * HH + h];
    }
    if (tid < 64) maskS[tid] = mask[b * SS + k0 + tid];
    __syncthreads();

    const int ty = tid >> 4, tx = tid & 15;
    float acc[4][4] = {};
#pragma unroll 8
    for (int d = 0; d < 64; ++d) {
        float a_[4], b_[4];
#pragma unroll
        for (int i = 0; i < 4; ++i) a_[i] = Qs[ty * 4 + i][d];
#pragma unroll
        for (int j = 0; j < 4; ++j) b_[j] = Ks[tx * 4 + j][d];
#pragma unroll
        for (int i = 0; i < 4; ++i)
#pragma unroll
            for (int j = 0; j < 4; ++j)
                acc[i][j] = fmaf(a_[i], b_[j], acc[i][j]);
    }

#pragma unroll
    for (int i = 0; i < 4; ++i) {
        const int qi = ty * 4 + i;
        float4 o;
#pragma unroll
        for (int j = 0; j < 4; ++j) {
            const int kj = tx * 4 + j;
            float s = acc[i][j] * 0.125f + biasS[kj - qi + 63];
            s = (maskS[kj] == 0) ? -1e9f : s;
            (&o.x)[j] = s;
        }
        *(float4*)(P + ((size_t)(bh * SS + q0 + qi)) * SS + k0 + tx * 4) = o;
    }
}

// ---------------------------------------------------------------------------
// Kernel 3: in-place row softmax over P (row length 1024). 256 thr/row.
// ---------------------------------------------------------------------------
__global__ __launch_bounds__(256)
void k_softmax(float* __restrict__ P) {
    const size_t row = blockIdx.x;
    float4* p = reinterpret_cast<float4*>(P + row * 1024);
    const int tid = threadIdx.x;
    float4 v = p[tid];

    float m = fmaxf(fmaxf(v.x, v.y), fmaxf(v.z, v.w));
#pragma unroll
    for (int off = 32; off > 0; off >>= 1)
        m = fmaxf(m, __shfl_xor(m, off, 64));

    __shared__ float redm[4], reds[4];
    const int wave = tid >> 6, lane = tid & 63;
    if (lane == 0) redm[wave] = m;
    __syncthreads();
    m = fmaxf(fmaxf(redm[0], redm[1]), fmaxf(redm[2], redm[3]));

    const float e0 = expf(v.x - m), e1 = expf(v.y - m);
    const float e2 = expf(v.z - m), e3 = expf(v.w - m);
    float ssum = e0 + e1 + e2 + e3;
#pragma unroll
    for (int off = 32; off > 0; off >>= 1)
        ssum += __shfl_xor(ssum, off, 64);
    if (lane == 0) reds[wave] = ssum;
    __syncthreads();
    ssum = reds[0] + reds[1] + reds[2] + reds[3];

    const float inv = 1.0f / ssum;
    p[tid] = make_float4(e0 * inv, e1 * inv, e2 * inv, e3 * inv);
}

// ---------------------------------------------------------------------------
// Kernel 4: AO = P @ V for each (b,h). M=1024(q), N=64(d), K=1024(k).
// Block: 64 q-rows x full 64 d-cols, BK=16.
// ---------------------------------------------------------------------------
__global__ __launch_bounds__(256)
void k_pv(const float* __restrict__ P,
          const float* __restrict__ V,
          float* __restrict__ AO) {
    __shared__ float As[16][68];  // [k][q]
    __shared__ float Bs[16][68];  // [k][d]

    const int bh = blockIdx.y;
    const int b = bh >> 4, h = bh & 15;
    const int q0 = blockIdx.x * 64;
    const int tid = threadIdx.x;
    const int ty = tid >> 4, tx = tid & 15;

    const int lrA = tid >> 2;        // q 0..63
    const int lcA = (tid & 3) * 4;   // k 0..15
    const int lrB = tid >> 4;        // k 0..15
    const int lcB = (tid & 15) * 4;  // d 0..63

    float acc[4][4] = {};

    for (int k0 = 0; k0 < SS; k0 += 16) {
        float4 a = *(const float4*)(P + ((size_t)(bh * SS + q0 + lrA)) * SS + k0 + lcA);
        float4 bvec = *(const float4*)(V + ((size_t)bh * SS + k0 + lrB) * DK + lcB);
        __syncthreads();
        As[lcA + 0][lrA] = a.x; As[lcA + 1][lrA] = a.y;
        As[lcA + 2][lrA] = a.z; As[lcA + 3][lrA] = a.w;
        *(float4*)&Bs[lrB][lcB] = bvec;
        __syncthreads();
#pragma unroll
        for (int kk = 0; kk < 16; ++kk) {
            float4 av = *(const float4*)&As[kk][ty * 4];
            float4 bv = *(const float4*)&Bs[kk][tx * 4];
            float a_[4] = {av.x, av.y, av.z, av.w};
            float b_[4] = {bv.x, bv.y, bv.z, bv.w};
#pragma unroll
            for (int i = 0; i < 4; ++i)
#pragma unroll
                for (int j = 0; j < 4; ++j)
                    acc[i][j] = fmaf(a_[i], b_[j], acc[i][j]);
        }
    }

    // AO[b, q, h*64 + d]  (row-major [MM, DM])
#pragma unroll
    for (int i = 0; i < 4; ++i) {
        const int q = q0 + ty * 4 + i;
        float4 o = make_float4(acc[i][0], acc[i][1], acc[i][2], acc[i][3]);
        *(float4*)(AO + ((size_t)(b * SS + q)) * DM + h * DK + tx * 4) = o;
    }
}

// ---------------------------------------------------------------------------
// Kernel 5: out = AO @ Wo^T  (M=4096, N=1024, K=1024), plain row-major out.
// ---------------------------------------------------------------------------
__global__ __launch_bounds__(256)
void k_out_proj(const float* __restrict__ A,
                const float* __restrict__ Wo,
                float* __restrict__ Out) {
    __shared__ float As[16][68];
    __shared__ float Bs[16][68];

    const int tid = threadIdx.x;
    const int m0 = blockIdx.y * 64;
    const int n0 = blockIdx.x * 64;
    const int lr = tid >> 2;
    const int lc = (tid & 3) * 4;
    const int ty = tid >> 4;
    const int tx = tid & 15;

    float acc[4][4] = {};

    for (int k0 = 0; k0 < DM; k0 += 16) {
        float4 a = *(const float4*)(A + (size_t)(m0 + lr) * DM + k0 + lc);
        float4 b = *(const float4*)(Wo + (size_t)(n0 + lr) * DM + k0 + lc);
        __syncthreads();
        As[lc + 0][lr] = a.x; As[lc + 1][lr] = a.y; As[lc + 2][lr] = a.z; As[lc + 3][lr] = a.w;
        Bs[lc + 0][lr] = b.x; Bs[lc + 1][lr] = b.y; Bs[lc + 2][lr] = b.z; Bs[lc + 3][lr] = b.w;
        __syncthreads();
#pragma unroll
        for (int kk = 0; kk < 16; ++kk) {
            float4 av = *(const float4*)&As[kk][ty * 4];
            float4 bv = *(const float4*)&Bs[kk][tx * 4];
            float a_[4] = {av.x, av.y, av.z, av.w};
            float b_[4] = {bv.x, bv.y, bv.z, bv.w};
#pragma unroll
            for (int i = 0; i < 4; ++i)
#pragma unroll
                for (int j = 0; j < 4; ++j)
                    acc[i][j] = fmaf(a_[i], b_[j], acc[i][j]);
        }
    }

#pragma unroll
    for (int i = 0; i < 4; ++i) {
        float4 o = make_float4(acc[i][0], acc[i][1], acc[i][2], acc[i][3]);
        *(float4*)(Out + (size_t)(m0 + ty * 4 + i) * DM + n0 + tx * 4) = o;
    }
}

// ---------------------------------------------------------------------------
extern "C" void kernel_launch(void* const* d_in, const int* in_sizes, int n_in,
                              void* d_out, int out_size, void* d_ws, size_t ws_size,
                              hipStream_t stream) {
    const float* X    = (const float*)d_in[0];  // [4,1024,1024]
    const int*   mask = (const int*)d_in[1];    // [4,1,1,1024]
    const float* Wq   = (const float*)d_in[2];  // [1024,1024]
    const float* Wk   = (const float*)d_in[3];
    const float* Wv   = (const float*)d_in[4];
    const float* Wo   = (const float*)d_in[5];
    const float* rb   = (const float*)d_in[6];  // [32,16]

    float* out = (float*)d_out;                       // output [4,1024,1024]
    float* P   = out + (size_t)BB * SS * DM;          // attn_weights [4,16,1024,1024]

    float* ws = (float*)d_ws;
    float* Q  = ws;                       // [B,H,S,D] 16 MB
    float* Kt = ws + (size_t)4194304;     // 16 MB
    float* Vt = ws + (size_t)8388608;     // 16 MB
    float* AO = ws;                       // reuse Q's slot (Q dead after k_scores)

    k_proj_qkv<<<dim3(DM / 64, MM / 64, 3), 256, 0, stream>>>(X, Wq, Wk, Wv, Q, Kt, Vt);
    k_scores<<<dim3(SS / 64, SS / 64, BB * HH), 256, 0, stream>>>(Q, Kt, mask, rb, P);
    k_softmax<<<dim3(BB * HH * SS), 256, 0, stream>>>(P);
    k_pv<<<dim3(SS / 64, BB * HH), 256, 0, stream>>>(P, Vt, AO);
    k_out_proj<<<dim3(DM / 64, MM / 64), 256, 0, stream>>>(AO, Wo, out);
}

// Round 2
// 659.170 us; speedup vs baseline: 1.7474x; 1.7474x over previous
//
#include <hip/hip_runtime.h>
#include <hip/hip_bf16.h>

#define BB 4
#define SS 1024
#define HH 16
#define DK 64
#define DM 1024
#define MM (BB * SS)  // 4096

typedef __attribute__((ext_vector_type(8))) short bh8_t;  // 8 bf16 (4 VGPRs)
typedef __attribute__((ext_vector_type(4))) float f4_t;   // 4 fp32

#define MFMA(a, b, c) __builtin_amdgcn_mfma_f32_16x16x32_bf16(a, b, c, 0, 0, 0)

// fp32 -> bf16 (RNE) raw bits
__device__ __forceinline__ short f2bf(float f) {
    unsigned u = __builtin_bit_cast(unsigned, f);
    u = (u + 0x7FFFu + ((u >> 16) & 1u)) >> 16;
    return (short)u;
}
__device__ __forceinline__ float bf2f(short h) {
    unsigned u = ((unsigned)(unsigned short)h) << 16;
    return __builtin_bit_cast(float, u);
}

// T5 relative position bucket (bidirectional); rel = k - q
__device__ __forceinline__ int rel_bucket(int rel) {
    int n = -rel;
    int ret = 0;
    if (n < 0) { ret = 16; n = -n; }
    int v;
    if (n < 8) {
        v = n;
    } else {
        float t = logf((float)n * 0.125f) / 2.7725887298583984f * 8.0f;
        v = 8 + (int)t;
        if (v > 15) v = 15;
    }
    return ret + v;
}

// ---------------------------------------------------------------------------
// Q/K projection, split-bf16 (hi+lo, 3 MFMAs) for ~fp32 accuracy.
// C = X[4096x1024] * W^T[1024x1024]; outputs split pairs in [B,H,S,DK].
// 128x128 tile, BK=32, 256 thr = 4 waves (2x2 of 64x64).
// ---------------------------------------------------------------------------
__global__ __launch_bounds__(256)
void k_proj_qk(const float* __restrict__ X, const float* __restrict__ Wq,
               const float* __restrict__ Wk,
               short* __restrict__ Qh, short* __restrict__ Ql,
               short* __restrict__ Kh, short* __restrict__ Kl) {
    const int z = blockIdx.z;
    const float* W = z ? Wk : Wq;
    short* Oh = z ? Kh : Qh;
    short* Ol = z ? Kl : Ql;

    __shared__ short Ah[128][40], Al[128][40], Bh[128][40], Bl[128][40];

    const int tid = threadIdx.x;
    const int m0 = blockIdx.y * 128, n0 = blockIdx.x * 128;
    const int wave = tid >> 6, lane = tid & 63;
    const int quad = lane >> 4, lm = lane & 15;
    const int wm = (wave >> 1) * 64, wn = (wave & 1) * 64;
    const int r = tid >> 1, sg = (tid & 1) * 16;

    f4_t acc[4][4];
#pragma unroll
    for (int i = 0; i < 4; ++i)
#pragma unroll
        for (int j = 0; j < 4; ++j) acc[i][j] = (f4_t){0.f, 0.f, 0.f, 0.f};

    for (int k0 = 0; k0 < DM; k0 += 32) {
        f4_t xa[4], wb[4];
#pragma unroll
        for (int u = 0; u < 4; ++u) {
            xa[u] = *(const f4_t*)(X + (size_t)(m0 + r) * DM + k0 + sg + u * 4);
            wb[u] = *(const f4_t*)(W + (size_t)(n0 + r) * DM + k0 + sg + u * 4);
        }
        __syncthreads();
#pragma unroll
        for (int u = 0; u < 4; ++u) {
            short4 hh, ll;
            hh.x = f2bf(xa[u][0]); ll.x = f2bf(xa[u][0] - bf2f(hh.x));
            hh.y = f2bf(xa[u][1]); ll.y = f2bf(xa[u][1] - bf2f(hh.y));
            hh.z = f2bf(xa[u][2]); ll.z = f2bf(xa[u][2] - bf2f(hh.z));
            hh.w = f2bf(xa[u][3]); ll.w = f2bf(xa[u][3] - bf2f(hh.w));
            *(short4*)&Ah[r][sg + u * 4] = hh;
            *(short4*)&Al[r][sg + u * 4] = ll;
            hh.x = f2bf(wb[u][0]); ll.x = f2bf(wb[u][0] - bf2f(hh.x));
            hh.y = f2bf(wb[u][1]); ll.y = f2bf(wb[u][1] - bf2f(hh.y));
            hh.z = f2bf(wb[u][2]); ll.z = f2bf(wb[u][2] - bf2f(hh.z));
            hh.w = f2bf(wb[u][3]); ll.w = f2bf(wb[u][3] - bf2f(hh.w));
            *(short4*)&Bh[r][sg + u * 4] = hh;
            *(short4*)&Bl[r][sg + u * 4] = ll;
        }
        __syncthreads();

        bh8_t ah[4], al[4];
#pragma unroll
        for (int i = 0; i < 4; ++i) {
            ah[i] = *(const bh8_t*)&Ah[wm + i * 16 + lm][quad * 8];
            al[i] = *(const bh8_t*)&Al[wm + i * 16 + lm][quad * 8];
        }
#pragma unroll
        for (int j = 0; j < 4; ++j) {
            bh8_t bhj = *(const bh8_t*)&Bh[wn + j * 16 + lm][quad * 8];
            bh8_t blj = *(const bh8_t*)&Bl[wn + j * 16 + lm][quad * 8];
#pragma unroll
            for (int i = 0; i < 4; ++i) {
                acc[i][j] = MFMA(al[i], bhj, acc[i][j]);
                acc[i][j] = MFMA(ah[i], blj, acc[i][j]);
                acc[i][j] = MFMA(ah[i], bhj, acc[i][j]);
            }
        }
    }

#pragma unroll
    for (int i = 0; i < 4; ++i)
#pragma unroll
        for (int j = 0; j < 4; ++j)
#pragma unroll
            for (int g = 0; g < 4; ++g) {
                const int row = m0 + wm + i * 16 + quad * 4 + g;
                const int col = n0 + wn + j * 16 + lm;
                const int b = row >> 10, s = row & 1023;
                const int hd = col >> 6, dk = col & 63;
                const float v = acc[i][j][g];
                const short vh = f2bf(v);
                const short vl = f2bf(v - bf2f(vh));
                const size_t o = ((size_t)((b * HH + hd) * SS + s)) * DK + dk;
                Oh[o] = vh;
                Ol[o] = vl;
            }
}

// ---------------------------------------------------------------------------
// V projection, single bf16; writes transposed Vt[bh][dk][s] for pv staging.
// ---------------------------------------------------------------------------
__global__ __launch_bounds__(256)
void k_proj_v(const float* __restrict__ X, const float* __restrict__ Wv,
              short* __restrict__ Vt) {
    __shared__ short As[128][40], Bs[128][40];

    const int tid = threadIdx.x;
    const int m0 = blockIdx.y * 128, n0 = blockIdx.x * 128;
    const int wave = tid >> 6, lane = tid & 63;
    const int quad = lane >> 4, lm = lane & 15;
    const int wm = (wave >> 1) * 64, wn = (wave & 1) * 64;
    const int r = tid >> 1, sg = (tid & 1) * 16;

    f4_t acc[4][4];
#pragma unroll
    for (int i = 0; i < 4; ++i)
#pragma unroll
        for (int j = 0; j < 4; ++j) acc[i][j] = (f4_t){0.f, 0.f, 0.f, 0.f};

    for (int k0 = 0; k0 < DM; k0 += 32) {
        f4_t xa[4], wb[4];
#pragma unroll
        for (int u = 0; u < 4; ++u) {
            xa[u] = *(const f4_t*)(X + (size_t)(m0 + r) * DM + k0 + sg + u * 4);
            wb[u] = *(const f4_t*)(Wv + (size_t)(n0 + r) * DM + k0 + sg + u * 4);
        }
        __syncthreads();
#pragma unroll
        for (int u = 0; u < 4; ++u) {
            short4 hh;
            hh.x = f2bf(xa[u][0]); hh.y = f2bf(xa[u][1]);
            hh.z = f2bf(xa[u][2]); hh.w = f2bf(xa[u][3]);
            *(short4*)&As[r][sg + u * 4] = hh;
            hh.x = f2bf(wb[u][0]); hh.y = f2bf(wb[u][1]);
            hh.z = f2bf(wb[u][2]); hh.w = f2bf(wb[u][3]);
            *(short4*)&Bs[r][sg + u * 4] = hh;
        }
        __syncthreads();

        bh8_t ah[4];
#pragma unroll
        for (int i = 0; i < 4; ++i)
            ah[i] = *(const bh8_t*)&As[wm + i * 16 + lm][quad * 8];
#pragma unroll
        for (int j = 0; j < 4; ++j) {
            bh8_t bhj = *(const bh8_t*)&Bs[wn + j * 16 + lm][quad * 8];
#pragma unroll
            for (int i = 0; i < 4; ++i) acc[i][j] = MFMA(ah[i], bhj, acc[i][j]);
        }
    }

#pragma unroll
    for (int i = 0; i < 4; ++i)
#pragma unroll
        for (int j = 0; j < 4; ++j)
#pragma unroll
            for (int g = 0; g < 4; ++g) {
                const int row = m0 + wm + i * 16 + quad * 4 + g;
                const int col = n0 + wn + j * 16 + lm;
                const int b = row >> 10, s = row & 1023;
                const int hd = col >> 6, dk = col & 63;
                Vt[((size_t)((b * HH + hd) * DK + dk)) * SS + s] = f2bf(acc[i][j][g]);
            }
}

// ---------------------------------------------------------------------------
// Scores: S = (Qh+Ql)(Kh+Kl)^T / 8 + bias, mask; split-bf16 (3 MFMAs).
// 128x128 tile per (bh); K-dim = 64 (2 MFMA k-steps). Writes fp32 raw P.
// ---------------------------------------------------------------------------
__global__ __launch_bounds__(256)
void k_scores(const short* __restrict__ Qh, const short* __restrict__ Ql,
              const short* __restrict__ Kh, const short* __restrict__ Kl,
              const int* __restrict__ mask, const float* __restrict__ rb,
              float* __restrict__ P) {
    __shared__ short Qhs[128][72], Qls[128][72], Khs[128][72], Kls[128][72];
    __shared__ float biasS[256];
    __shared__ int maskS[128];

    const int bh = blockIdx.z, b = bh >> 4, hd = bh & 15;
    const int q0 = blockIdx.y * 128, k0 = blockIdx.x * 128;
    const int tid = threadIdx.x;
    const int wave = tid >> 6, lane = tid & 63;
    const int quad = lane >> 4, lm = lane & 15;
    const int wm = (wave >> 1) * 64, wn = (wave & 1) * 64;

    {
        const int r = tid >> 1, sg = (tid & 1) * 32;
        const size_t qo = ((size_t)bh * SS + q0 + r) * DK + sg;
        const size_t ko = ((size_t)bh * SS + k0 + r) * DK + sg;
#pragma unroll
        for (int u = 0; u < 4; ++u) {
            *(uint4*)&Qhs[r][sg + u * 8] = *(const uint4*)(Qh + qo + u * 8);
            *(uint4*)&Qls[r][sg + u * 8] = *(const uint4*)(Ql + qo + u * 8);
            *(uint4*)&Khs[r][sg + u * 8] = *(const uint4*)(Kh + ko + u * 8);
            *(uint4*)&Kls[r][sg + u * 8] = *(const uint4*)(Kl + ko + u * 8);
        }
    }
    if (tid < 255) biasS[tid] = rb[rel_bucket(k0 - q0 + tid - 127) * HH + hd];
    if (tid < 128) maskS[tid] = mask[b * SS + k0 + tid];
    __syncthreads();

    f4_t acc[4][4];
#pragma unroll
    for (int i = 0; i < 4; ++i)
#pragma unroll
        for (int j = 0; j < 4; ++j) acc[i][j] = (f4_t){0.f, 0.f, 0.f, 0.f};

#pragma unroll
    for (int ks = 0; ks < 2; ++ks) {
        bh8_t ah[4], al[4];
#pragma unroll
        for (int i = 0; i < 4; ++i) {
            ah[i] = *(const bh8_t*)&Qhs[wm + i * 16 + lm][ks * 32 + quad * 8];
            al[i] = *(const bh8_t*)&Qls[wm + i * 16 + lm][ks * 32 + quad * 8];
        }
#pragma unroll
        for (int j = 0; j < 4; ++j) {
            bh8_t bhj = *(const bh8_t*)&Khs[wn + j * 16 + lm][ks * 32 + quad * 8];
            bh8_t blj = *(const bh8_t*)&Kls[wn + j * 16 + lm][ks * 32 + quad * 8];
#pragma unroll
            for (int i = 0; i < 4; ++i) {
                acc[i][j] = MFMA(al[i], bhj, acc[i][j]);
                acc[i][j] = MFMA(ah[i], blj, acc[i][j]);
                acc[i][j] = MFMA(ah[i], bhj, acc[i][j]);
            }
        }
    }

#pragma unroll
    for (int i = 0; i < 4; ++i)
#pragma unroll
        for (int j = 0; j < 4; ++j)
#pragma unroll
            for (int g = 0; g < 4; ++g) {
                const int rowl = wm + i * 16 + quad * 4 + g;
                const int coll = wn + j * 16 + lm;
                float s = acc[i][j][g] * 0.125f + biasS[coll - rowl + 127];
                s = (maskS[coll] == 0) ? -1e9f : s;
                P[((size_t)bh * SS + q0 + rowl) * SS + k0 + coll] = s;
            }
}

// ---------------------------------------------------------------------------
// In-place row softmax over P (rows of 1024), fp32.
// ---------------------------------------------------------------------------
__global__ __launch_bounds__(256)
void k_softmax(float* __restrict__ P) {
    const size_t row = blockIdx.x;
    float4* p = reinterpret_cast<float4*>(P + row * 1024);
    const int tid = threadIdx.x;
    float4 v = p[tid];

    float m = fmaxf(fmaxf(v.x, v.y), fmaxf(v.z, v.w));
#pragma unroll
    for (int off = 32; off > 0; off >>= 1) m = fmaxf(m, __shfl_xor(m, off, 64));

    __shared__ float redm[4], reds[4];
    const int wave = tid >> 6, lane = tid & 63;
    if (lane == 0) redm[wave] = m;
    __syncthreads();
    m = fmaxf(fmaxf(redm[0], redm[1]), fmaxf(redm[2], redm[3]));

    const float e0 = expf(v.x - m), e1 = expf(v.y - m);
    const float e2 = expf(v.z - m), e3 = expf(v.w - m);
    float ssum = e0 + e1 + e2 + e3;
#pragma unroll
    for (int off = 32; off > 0; off >>= 1) ssum += __shfl_xor(ssum, off, 64);
    if (lane == 0) reds[wave] = ssum;
    __syncthreads();
    ssum = reds[0] + reds[1] + reds[2] + reds[3];

    const float inv = 1.0f / ssum;
    p[tid] = make_float4(e0 * inv, e1 * inv, e2 * inv, e3 * inv);
}

// ---------------------------------------------------------------------------
// AO = P @ V per (bh). P fp32 converted inline to bf16; Vt pre-transposed.
// M-tile 128(q), N = 64(dk), BK=32; 4 waves x 32 rows. AO written bf16.
// ---------------------------------------------------------------------------
__global__ __launch_bounds__(256)
void k_pv(const float* __restrict__ P, const short* __restrict__ Vt,
          short* __restrict__ AO) {
    __shared__ short As[128][40];
    __shared__ short Bs[64][40];

    const int bh = blockIdx.y, b = bh >> 4, hd = bh & 15;
    const int q0 = blockIdx.x * 128;
    const int tid = threadIdx.x;
    const int wave = tid >> 6, lane = tid & 63;
    const int quad = lane >> 4, lm = lane & 15;
    const int wm = wave * 32;
    const int rA = tid >> 1, sgA = (tid & 1) * 16;
    const int rB = tid >> 2, sgB = (tid & 3) * 8;

    f4_t acc[2][4];
#pragma unroll
    for (int i = 0; i < 2; ++i)
#pragma unroll
        for (int j = 0; j < 4; ++j) acc[i][j] = (f4_t){0.f, 0.f, 0.f, 0.f};

    for (int k0 = 0; k0 < SS; k0 += 32) {
        f4_t pr[4];
#pragma unroll
        for (int u = 0; u < 4; ++u)
            pr[u] = *(const f4_t*)(P + ((size_t)bh * SS + q0 + rA) * SS + k0 + sgA + u * 4);
        uint4 vb = *(const uint4*)(Vt + ((size_t)bh * DK + rB) * SS + k0 + sgB);
        __syncthreads();
#pragma unroll
        for (int u = 0; u < 4; ++u) {
            short4 hh;
            hh.x = f2bf(pr[u][0]); hh.y = f2bf(pr[u][1]);
            hh.z = f2bf(pr[u][2]); hh.w = f2bf(pr[u][3]);
            *(short4*)&As[rA][sgA + u * 4] = hh;
        }
        *(uint4*)&Bs[rB][sgB] = vb;
        __syncthreads();

        bh8_t af0 = *(const bh8_t*)&As[wm + lm][quad * 8];
        bh8_t af1 = *(const bh8_t*)&As[wm + 16 + lm][quad * 8];
#pragma unroll
        for (int j = 0; j < 4; ++j) {
            bh8_t bf = *(const bh8_t*)&Bs[j * 16 + lm][quad * 8];
            acc[0][j] = MFMA(af0, bf, acc[0][j]);
            acc[1][j] = MFMA(af1, bf, acc[1][j]);
        }
    }

#pragma unroll
    for (int i = 0; i < 2; ++i)
#pragma unroll
        for (int j = 0; j < 4; ++j)
#pragma unroll
            for (int g = 0; g < 4; ++g) {
                const int s = q0 + wm + i * 16 + quad * 4 + g;
                const int dk = j * 16 + lm;
                AO[((size_t)(b * SS + s)) * DM + hd * DK + dk] = f2bf(acc[i][j][g]);
            }
}

// ---------------------------------------------------------------------------
// out = AO(bf16) @ Wo^T (fp32 converted inline). 128x128 tile, fp32 out.
// ---------------------------------------------------------------------------
__global__ __launch_bounds__(256)
void k_out(const short* __restrict__ A, const float* __restrict__ Wo,
           float* __restrict__ Out) {
    __shared__ short As[128][40], Bs[128][40];

    const int tid = threadIdx.x;
    const int m0 = blockIdx.y * 128, n0 = blockIdx.x * 128;
    const int wave = tid >> 6, lane = tid & 63;
    const int quad = lane >> 4, lm = lane & 15;
    const int wm = (wave >> 1) * 64, wn = (wave & 1) * 64;
    const int r = tid >> 1, sg = (tid & 1) * 16;

    f4_t acc[4][4];
#pragma unroll
    for (int i = 0; i < 4; ++i)
#pragma unroll
        for (int j = 0; j < 4; ++j) acc[i][j] = (f4_t){0.f, 0.f, 0.f, 0.f};

    for (int k0 = 0; k0 < DM; k0 += 32) {
        uint4 a0 = *(const uint4*)(A + (size_t)(m0 + r) * DM + k0 + sg);
        uint4 a1 = *(const uint4*)(A + (size_t)(m0 + r) * DM + k0 + sg + 8);
        f4_t wb[4];
#pragma unroll
        for (int u = 0; u < 4; ++u)
            wb[u] = *(const f4_t*)(Wo + (size_t)(n0 + r) * DM + k0 + sg + u * 4);
        __syncthreads();
        *(uint4*)&As[r][sg] = a0;
        *(uint4*)&As[r][sg + 8] = a1;
#pragma unroll
        for (int u = 0; u < 4; ++u) {
            short4 hh;
            hh.x = f2bf(wb[u][0]); hh.y = f2bf(wb[u][1]);
            hh.z = f2bf(wb[u][2]); hh.w = f2bf(wb[u][3]);
            *(short4*)&Bs[r][sg + u * 4] = hh;
        }
        __syncthreads();

        bh8_t ah[4];
#pragma unroll
        for (int i = 0; i < 4; ++i)
            ah[i] = *(const bh8_t*)&As[wm + i * 16 + lm][quad * 8];
#pragma unroll
        for (int j = 0; j < 4; ++j) {
            bh8_t bhj = *(const bh8_t*)&Bs[wn + j * 16 + lm][quad * 8];
#pragma unroll
            for (int i = 0; i < 4; ++i) acc[i][j] = MFMA(ah[i], bhj, acc[i][j]);
        }
    }

#pragma unroll
    for (int i = 0; i < 4; ++i)
#pragma unroll
        for (int j = 0; j < 4; ++j)
#pragma unroll
            for (int g = 0; g < 4; ++g)
                Out[(size_t)(m0 + wm + i * 16 + quad * 4 + g) * DM + n0 + wn + j * 16 + lm] =
                    acc[i][j][g];
}

// ---------------------------------------------------------------------------
extern "C" void kernel_launch(void* const* d_in, const int* in_sizes, int n_in,
                              void* d_out, int out_size, void* d_ws, size_t ws_size,
                              hipStream_t stream) {
    const float* X    = (const float*)d_in[0];
    const int*   mask = (const int*)d_in[1];
    const float* Wq   = (const float*)d_in[2];
    const float* Wk   = (const float*)d_in[3];
    const float* Wv   = (const float*)d_in[4];
    const float* Wo   = (const float*)d_in[5];
    const float* rb   = (const float*)d_in[6];

    float* out = (float*)d_out;
    float* P   = out + (size_t)BB * SS * DM;  // attn_weights region of d_out

    short* ws = (short*)d_ws;
    short* Qh = ws;                         // 8 MB
    short* Ql = ws + (size_t)4194304;       // 8 MB
    short* Kh = ws + (size_t)8388608;       // 8 MB
    short* Kl = ws + (size_t)12582912;      // 8 MB
    short* Vt = ws + (size_t)16777216;      // 8 MB (transposed [bh][dk][s])
    short* AO = ws;                         // reuse Qh slot (dead after scores)

    k_proj_qk<<<dim3(8, 32, 2), 256, 0, stream>>>(X, Wq, Wk, Qh, Ql, Kh, Kl);
    k_proj_v <<<dim3(8, 32, 1), 256, 0, stream>>>(X, Wv, Vt);
    k_scores <<<dim3(8, 8, BB * HH), 256, 0, stream>>>(Qh, Ql, Kh, Kl, mask, rb, P);
    k_softmax<<<dim3(BB * HH * SS), 256, 0, stream>>>(P);
    k_pv     <<<dim3(8, BB * HH), 256, 0, stream>>>(P, Vt, AO);
    k_out    <<<dim3(8, 32), 256, 0, stream>>>(AO, Wo, out);
}